// Round 1
// baseline (641.547 us; speedup 1.0000x reference)
//
#include <hip/hip_runtime.h>

#define EPSILON 0.001f
#define NSUP 601

// ---------------------------------------------------------------------------
// Kernel 1: zero the whole 630 MB output. Pure store-BW bound.
// Grid-stride float4 stores (16 B/lane coalescing sweet spot).
// ---------------------------------------------------------------------------
__global__ void zero_kernel(float4* __restrict__ out4, long long n4,
                            float* __restrict__ out_tail, long long n_tail_start,
                            long long n_total) {
    long long i = (long long)blockIdx.x * blockDim.x + threadIdx.x;
    long long stride = (long long)gridDim.x * blockDim.x;
    const float4 z = make_float4(0.f, 0.f, 0.f, 0.f);
    for (long long j = i; j < n4; j += stride) {
        out4[j] = z;
    }
    // tail (out_size % 4) — not hit for this problem (157548544 % 4 == 0)
    for (long long j = n_tail_start + i; j < n_total; j += stride) {
        out_tail[j] = 0.f;
    }
}

// ---------------------------------------------------------------------------
// Kernel 2: one thread per (b,k) row — compute t, indices, write two probs.
// Supports are unit-spaced linspace(-300,300,601): searchsorted(right)-1 ==
// floor(t)+300. Load actual support values from memory for the p arithmetic
// (guards against linspace rounding fuzz); they live in L1/L2 after first use.
// Writing lower then upper in program order reproduces the reference's
// "upper overwrites lower on collision" semantics.
// ---------------------------------------------------------------------------
__global__ void twohot_kernel(const float* __restrict__ x,
                              const float* __restrict__ supports,
                              float* __restrict__ out, int nrows) {
    int i = blockIdx.x * blockDim.x + threadIdx.x;
    if (i >= nrows) return;
    float v = x[i];
    float s = (v > 0.f) ? 1.f : ((v < 0.f) ? -1.f : 0.f);
    float t = s * (sqrtf(fabsf(v) + 1.f) - 1.f + EPSILON * v);

    int idx = (int)floorf(t) + 300;          // searchsorted(right) - 1
    int lower = idx < 0 ? 0 : (idx > NSUP - 1 ? NSUP - 1 : idx);
    int upper = (lower + 1 > NSUP - 1) ? NSUP - 1 : lower + 1;

    float ls = supports[lower];
    float us = supports[upper];
    float p_low = (us - t) / (us - ls);      // denom == 1.0 in-range
    float p_high = 1.f - p_low;

    float* row = out + (long long)i * NSUP;
    row[lower] = p_low;   // program order: upper write wins on collision
    row[upper] = p_high;
}

extern "C" void kernel_launch(void* const* d_in, const int* in_sizes, int n_in,
                              void* d_out, int out_size, void* d_ws, size_t ws_size,
                              hipStream_t stream) {
    const float* tv = (const float*)d_in[0];
    const float* supports = (const float*)d_in[1];
    float* out = (float*)d_out;

    long long n_total = (long long)out_size;
    long long n4 = n_total / 4;

    // Zero pass: 8192 blocks x 256 threads -> 2M threads, ~19 float4 stores each.
    zero_kernel<<<8192, 256, 0, stream>>>((float4*)d_out, n4, out, n4 * 4, n_total);

    int nrows = in_sizes[0];   // 4096 * 64 = 262144
    twohot_kernel<<<(nrows + 255) / 256, 256, 0, stream>>>(tv, supports, out, nrows);
}